// Round 12
// baseline (380.113 us; speedup 1.0000x reference)
//
#include <hip/hip_runtime.h>
#include <stdint.h>

// Problem constants (from reference): B=8, L=4096, D=1024, S=255
constexpr int kB = 8;
constexpr int kL = 4096;
constexpr int kD = 1024;
constexpr int kS = 255;
constexpr int kM = kB * kL;   // 32768 rows of A / out
constexpr int kK = 2 * kD;    // 2048 reduction dim
constexpr int kN = kD;        // 1024 output features

typedef __bf16 bf16x8 __attribute__((ext_vector_type(8)));
typedef float  f32x4  __attribute__((ext_vector_type(4)));

// ---- workspace layout (bytes): W bf16 mirror + 4 KiB fp32 zero page ----
constexpr size_t WS_W    = 0;                         // [1024][2048] bf16 = 4 MiB
constexpr size_t WS_ZP   = (size_t)kN * kK * 2;       // 4,194,304
constexpr size_t WS_NEED = WS_ZP + 4096;              // zero page 4 KiB

// fp32 pair -> packed bf16x2, round-half-up (validated R0-R11; used for W)
__device__ __forceinline__ uint32_t pk_bf16x2(float a, float b) {
    uint32_t ua = __float_as_uint(a) + 0x8000u;
    uint32_t ub = __float_as_uint(b) + 0x8000u;
    return __builtin_amdgcn_perm(ub, ua, 0x07060302u);
}

// async global->LDS 16B per lane: dest = wave-uniform base + lane*16
__device__ __forceinline__ void async16(const void* g, void* l) {
    __builtin_amdgcn_global_load_lds(
        (const __attribute__((address_space(1))) uint32_t*)g,
        (__attribute__((address_space(3))) uint32_t*)l, 16, 0, 0);
}

#define WAITVM(n)  asm volatile("s_waitcnt vmcnt(" #n ")" ::: "memory")
#define WAITLGKM0  asm volatile("s_waitcnt lgkmcnt(0)" ::: "memory")

__device__ __forceinline__ void blockbar() {
    __builtin_amdgcn_sched_barrier(0);
    __builtin_amdgcn_s_barrier();
    __builtin_amdgcn_sched_barrier(0);
}

// ============ tiny prepass: W fp32 -> bf16 (4 MiB) + 4 KiB zero page ========
// (validated in R3/R4 rounds)
__global__ __launch_bounds__(256)
void cvt_w(const float4* __restrict__ W, uint4* __restrict__ WB,
           uint32_t* __restrict__ zp)
{
    if (blockIdx.x == 0) {
        for (int t = threadIdx.x; t < 1024; t += 256) zp[t] = 0u;  // 4 KB zeros
    }
    size_t i = (size_t)blockIdx.x * 256 + threadIdx.x;   // 262144 items exactly
    float4 a  = W[2 * i];
    float4 b2 = W[2 * i + 1];
    uint4 o;
    o.x = pk_bf16x2(a.x,  a.y);
    o.y = pk_bf16x2(a.z,  a.w);
    o.z = pk_bf16x2(b2.x, b2.y);
    o.w = pk_bf16x2(b2.z, b2.w);
    WB[i] = o;
}

// ===================== GEMM v10: fp32-A direct DMA, v7 schedule =============
// C[m,n] = relu( sum_k A[m,k]*W[n,k] + bias[n] ),  A = [words | sent-gather]
// v7's proven schedule (1 barrier/kstep, counted vmcnt, frag-linear LDS,
// setprio) with A staged as RAW FP32 via global_load_lds (no words/sents
// mirror; kills the 192 MB prepass round-trip). Conversion fp32->bf16 happens
// at fragment-read time (2x ds_read_b128 + 8 casts -> v_cvt_pk pairs).
// LDS: 3 buffers x {A 32KB fp32 + B 16KB bf16} = 144 KB (1 block/CU).
// A layout per buffer: [slab 0..15][h 0..1][lane16B] — frag read = two
// 1024B-linear wave reads (conflict-free). Staging inverse map per thread:
//   row  = mT*256 + j*64 + (w>>1)*16 + (lane&15)      (j = 0..3)
//   kbyte= quad*32 + (w&1)*16   (+ t*128 per kstep)
// dest  = A + j*8192 + w*1024 (+ HW lane*16)   — verified algebraically.
// vmcnt ledger (6 loads/kstep, stage(t+2) in PHASE A): at kstep-t mid,
// outstanding = stage(t+1)6 + stage(t+2)6; WAITVM(6) => tile t+1 complete,
// t+2 stays in flight. t>=62: WAITVM(0). Lifetimes: buffer overwritten at
// kstep t+1/t+2 phase A; all reads of it drained at the preceding kstep's
// WAITLGKM0 + barrier (one barrier separation, all waves).
__global__ __launch_bounds__(512, 2)
void wsib_gemm_v10(const float* __restrict__ words,   // [32768][1024] f32
                   const float* __restrict__ sents,   // [8*255][1024] f32
                   const uint8_t* __restrict__ WB,    // [1024][2048]  bf16
                   const float*   __restrict__ bias,
                   const int*     __restrict__ smap,
                   const uint8_t* __restrict__ zp,    // 4 KB zeros
                   float* __restrict__ out)
{
    __shared__ uint8_t lds[3][49152];   // [buf][A 32KB | B 16KB]

    const int tid  = threadIdx.x;
    const int w    = tid >> 6;           // wave 0..7
    const int lane = tid & 63;

    // XCD-aware bijective swizzle (proven FETCH halver, R8)
    const int lin = blockIdx.y * gridDim.x + blockIdx.x;   // 0..511
    const int swz = (lin & 7) * 64 + (lin >> 3);
    const int nT = swz & 3;              // 0..3
    const int mT = swz >> 2;             // 0..127

    const int wm = (w >> 2) * 128;       // 0 or 128
    const int wn = (w & 3) * 64;         // 0,64,128,192
    const int fr = lane & 15, quad = lane >> 4;
    const int lo16 = lane * 16;          // frag-linear lane offset
    const int slabA = (w >> 2) * 8;      // A slab base (16 slabs of 16 rows)
    const int slabB = (w & 3) * 4;       // B slab base

    float bv[4];
    #pragma unroll
    for (int ni = 0; ni < 4; ++ni) bv[ni] = bias[nT * 256 + wn + ni * 16 + fr];

    // ---- A staging sources (fp32, frag-linear inverse map) ----
    const int rloc = ((w >> 1) << 4) + fr;         // 0..63
    const int kbA  = quad * 32 + (w & 1) * 16;     // 0..112
    const int bIdx = (mT * 256) >> 12;             // tile never crosses batch
    const uint8_t* aw[4];
    const uint8_t* as[4];
    #pragma unroll
    for (int j = 0; j < 4; ++j) {
        const int row = mT * 256 + j * 64 + rloc;
        aw[j] = (const uint8_t*)(words + (size_t)row * kD) + kbA;
        const int s = smap[row];
        as[j] = (s >= 0) ? (const uint8_t*)(sents + (size_t)(bIdx * kS + s) * kD) + kbA
                         : zp + kbA;   // (t-32)*128 + kbA + 16 <= 4096: fits page
    }
    // ---- B staging sources (bf16, v7-identical) ----
    const int colb = quad * 16;
    const int r0 = w * 16 + fr;
    const uint8_t* pB0 = WB + (size_t)(nT * 256 + r0) * 4096 + colb;
    const uint8_t* pB1 = WB + (size_t)(nT * 256 + r0 + 128) * 4096 + colb;

    auto stage = [&](int buf, int t) {   // 6 loads: A j0..j3 (fp32), B j0,j1
        uint8_t* A  = (uint8_t*)lds[buf];
        uint8_t* Bb = A + 32768;
        #pragma unroll
        for (int j = 0; j < 4; ++j) {
            const uint8_t* s = (t < 32) ? aw[j] + t * 128 : as[j] + (t - 32) * 128;
            async16(s, A + j * 8192 + w * 1024);
        }
        async16(pB0 + t * 64, Bb + w * 1024);
        async16(pB1 + t * 64, Bb + 8192 + w * 1024);
    };

    // fp32 A-frag read + convert: two 1024B-linear wave reads, 8 casts
    auto readA = [&](const uint8_t* Ab, int slab) -> bf16x8 {
        f32x4 flo = *(const f32x4*)(Ab + slab * 2048 + lo16);
        f32x4 fhi = *(const f32x4*)(Ab + slab * 2048 + 1024 + lo16);
        bf16x8 r;
        #pragma unroll
        for (int i = 0; i < 4; ++i) { r[i] = (__bf16)flo[i]; r[i + 4] = (__bf16)fhi[i]; }
        return r;
    };

    f32x4 acc[8][4];
    #pragma unroll
    for (int i = 0; i < 8; ++i)
        #pragma unroll
        for (int j = 0; j < 4; ++j) acc[i][j] = (f32x4){0.f, 0.f, 0.f, 0.f};

    // ---- prologue: stage tiles 0,1; tile 0 complete; prime frags(0) ----
    stage(0, 0);
    stage(1, 1);
    WAITVM(6);
    blockbar();

    bf16x8 af[4], bfA[4], bfB[4];
    #pragma unroll
    for (int mi = 0; mi < 4; ++mi)
        af[mi] = readA((const uint8_t*)lds[0], slabA + mi);
    #pragma unroll
    for (int ni = 0; ni < 4; ++ni)
        bfA[ni] = *(const bf16x8*)((const uint8_t*)lds[0] + 32768 + (slabB + ni) * 1024 + lo16);

    // ---- main loop: 64 K-steps of 32, 1 barrier each ----
    auto kstep = [&](int t, int bufR, bf16x8 (&bfc)[4], bf16x8 (&bfn)[4]) {
        const int bufN = (bufR == 2) ? 0 : bufR + 1;   // (t+1)%3
        const int bufS = (bufN == 2) ? 0 : bufN + 1;   // (t+2)%3
        const uint8_t* Ab = (const uint8_t*)lds[bufR];

        // phase A: issue stage(t+2) early, read+cvt ag(t), MFMA-A
        if (t + 2 < 64) stage(bufS, t + 2);
        bf16x8 ag[4];
        #pragma unroll
        for (int mi = 0; mi < 4; ++mi)
            ag[mi] = readA(Ab, slabA + 4 + mi);
        __builtin_amdgcn_s_setprio(1);
        #pragma unroll
        for (int mi = 0; mi < 4; ++mi)
            #pragma unroll
            for (int ni = 0; ni < 4; ++ni)
                acc[mi][ni] = __builtin_amdgcn_mfma_f32_16x16x32_bf16(
                    af[mi], bfc[ni], acc[mi][ni], 0, 0, 0);
        __builtin_amdgcn_s_setprio(0);

        // mid: drain own ds_reads; tile t+1 DMA-complete; publish via barrier
        WAITLGKM0;
        if (t < 62) { WAITVM(6); } else { WAITVM(0); }
        blockbar();

        // phase B: read+cvt frags(t+1), MFMA-B
        if (t + 1 < 64) {
            const uint8_t* AbN = (const uint8_t*)lds[bufN];
            const uint8_t* BbN = AbN + 32768;
            #pragma unroll
            for (int ni = 0; ni < 4; ++ni)
                bfn[ni] = *(const bf16x8*)(BbN + (slabB + ni) * 1024 + lo16);
            #pragma unroll
            for (int mi = 0; mi < 4; ++mi)
                af[mi] = readA(AbN, slabA + mi);
        }
        __builtin_amdgcn_s_setprio(1);
        #pragma unroll
        for (int mi = 0; mi < 4; ++mi)
            #pragma unroll
            for (int ni = 0; ni < 4; ++ni)
                acc[mi + 4][ni] = __builtin_amdgcn_mfma_f32_16x16x32_bf16(
                    ag[mi], bfc[ni], acc[mi + 4][ni], 0, 0, 0);
        __builtin_amdgcn_s_setprio(0);
    };

    int bufR = 0;
    #pragma unroll 1
    for (int t2 = 0; t2 < 32; ++t2) {
        kstep(2 * t2, bufR, bfA, bfB);
        bufR = (bufR == 2) ? 0 : bufR + 1;
        kstep(2 * t2 + 1, bufR, bfB, bfA);
        bufR = (bufR == 2) ? 0 : bufR + 1;
    }

    // ---- epilogue: bias + relu, fp32 store ----
    // C/D layout (verified): col = lane&15, row = quad*4 + r
    const int rowBase = mT * 256 + wm + quad * 4;
    const int colBase = nT * 256 + wn + fr;
    #pragma unroll
    for (int mi = 0; mi < 8; ++mi) {
        #pragma unroll
        for (int ni = 0; ni < 4; ++ni) {
            const int col = colBase + ni * 16;
            #pragma unroll
            for (int r = 0; r < 4; ++r) {
                const int row = rowBase + mi * 16 + r;
                out[(size_t)row * kN + col] = fmaxf(acc[mi][ni][r] + bv[ni], 0.f);
            }
        }
    }
}

// ===================== fallback (R2 kernel, no-workspace path) ==============
#define TILE_M 128
#define TILE_N 128
#define TILE_K 32
#define LDS_STRIDE 20
__global__ __launch_bounds__(256)
void wsib_gemm_fb(const float* __restrict__ words, const float* __restrict__ sents,
                  const float* __restrict__ W, const float* __restrict__ bias,
                  const int* __restrict__ smap, float* __restrict__ out)
{
    __shared__ uint32_t Asm[TILE_M * LDS_STRIDE];
    __shared__ uint32_t Bsm[TILE_N * LDS_STRIDE];
    const int tid = threadIdx.x, nT = blockIdx.x, mT = blockIdx.y;
    const int sRow = tid >> 1, half = tid & 1;
    const int mRow = mT * TILE_M + sRow, bIdx = mRow >> 12;
    const float* wsrc = words + (size_t)mRow * kD + half * 16;
    const int sidx = smap[mRow];
    const float* ssrc = (sidx >= 0) ? sents + ((size_t)bIdx * kS + sidx) * kD + half * 16 : nullptr;
    const float* bsrc = W + (size_t)(nT * TILE_N + sRow) * kK + half * 16;
    uint32_t* adst = &Asm[sRow * LDS_STRIDE + half * 8];
    uint32_t* bdst = &Bsm[sRow * LDS_STRIDE + half * 8];
    const int lane = tid & 63, wv = tid >> 6;
    const int wm = (wv & 1) * 64, wn = (wv >> 1) * 64;
    const int fr = lane & 15, quad = lane >> 4;
    f32x4 acc[4][4];
    #pragma unroll
    for (int i = 0; i < 4; ++i)
        #pragma unroll
        for (int j = 0; j < 4; ++j) acc[i][j] = (f32x4){0.f, 0.f, 0.f, 0.f};
    float4 ra[4], rb[4];
    {
        const float4* pa = (const float4*)wsrc; const float4* pb = (const float4*)bsrc;
        #pragma unroll
        for (int i = 0; i < 4; ++i) { ra[i] = pa[i]; rb[i] = pb[i]; }
    }
    for (int k0 = 0; k0 < kK; k0 += TILE_K) {
        uint32_t pa[8], pb[8];
        #pragma unroll
        for (int i = 0; i < 4; ++i) {
            pa[2*i] = pk_bf16x2(ra[i].x, ra[i].y); pa[2*i+1] = pk_bf16x2(ra[i].z, ra[i].w);
            pb[2*i] = pk_bf16x2(rb[i].x, rb[i].y); pb[2*i+1] = pk_bf16x2(rb[i].z, rb[i].w);
        }
        __syncthreads();
        ((uint4*)adst)[0] = make_uint4(pa[0], pa[1], pa[2], pa[3]);
        ((uint4*)adst)[1] = make_uint4(pa[4], pa[5], pa[6], pa[7]);
        ((uint4*)bdst)[0] = make_uint4(pb[0], pb[1], pb[2], pb[3]);
        ((uint4*)bdst)[1] = make_uint4(pb[4], pb[5], pb[6], pb[7]);
        __syncthreads();
        const int k1 = k0 + TILE_K;
        if (k1 < kK) {
            const float* asrc = (k1 < kD) ? (wsrc + k1) : (ssrc ? (ssrc + (k1 - kD)) : nullptr);
            if (asrc) { const float4* p = (const float4*)asrc;
                #pragma unroll
                for (int i = 0; i < 4; ++i) ra[i] = p[i];
            } else {
                #pragma unroll
                for (int i = 0; i < 4; ++i) ra[i] = make_float4(0.f, 0.f, 0.f, 0.f);
            }
            const float4* p = (const float4*)(bsrc + k1);
            #pragma unroll
            for (int i = 0; i < 4; ++i) rb[i] = p[i];
        }
        bf16x8 af[4], bfv[4];
        #pragma unroll
        for (int mi = 0; mi < 4; ++mi)
            af[mi] = *(const bf16x8*)&Asm[(wm + mi * 16 + fr) * LDS_STRIDE + quad * 4];
        #pragma unroll
        for (int ni = 0; ni < 4; ++ni)
            bfv[ni] = *(const bf16x8*)&Bsm[(wn + ni * 16 + fr) * LDS_STRIDE + quad * 4];
        #pragma unroll
        for (int mi = 0; mi < 4; ++mi)
            #pragma unroll
            for (int ni = 0; ni < 4; ++ni)
                acc[mi][ni] = __builtin_amdgcn_mfma_f32_16x16x32_bf16(af[mi], bfv[ni], acc[mi][ni], 0, 0, 0);
    }
    const int rowBase = mT * TILE_M + wm, colBase = nT * TILE_N + wn;
    float bv[4];
    #pragma unroll
    for (int ni = 0; ni < 4; ++ni) bv[ni] = bias[colBase + ni * 16 + fr];
    #pragma unroll
    for (int mi = 0; mi < 4; ++mi)
        #pragma unroll
        for (int ni = 0; ni < 4; ++ni) {
            const int col = colBase + ni * 16 + fr;
            #pragma unroll
            for (int r = 0; r < 4; ++r) {
                const int row = rowBase + mi * 16 + quad * 4 + r;
                out[(size_t)row * kN + col] = fmaxf(acc[mi][ni][r] + bv[ni], 0.f);
            }
        }
}

extern "C" void kernel_launch(void* const* d_in, const int* in_sizes, int n_in,
                              void* d_out, int out_size, void* d_ws, size_t ws_size,
                              hipStream_t stream) {
    const float* words = (const float*)d_in[0];   // [8, 4096, 1024] f32
    const float* sents = (const float*)d_in[1];   // [8, 255, 1024]  f32
    const float* W     = (const float*)d_in[2];   // [1024, 2048]    f32
    const float* bias  = (const float*)d_in[3];   // [1024]          f32
    const int*   smap  = (const int*)d_in[4];     // [8, 4096]       i32
    float* out = (float*)d_out;                   // [8, 4096, 1024] f32

    if (ws_size >= WS_NEED) {
        uint8_t* ws = (uint8_t*)d_ws;
        uint4* WBv    = (uint4*)(ws + WS_W);
        uint32_t* zp  = (uint32_t*)(ws + WS_ZP);
        cvt_w<<<1024, 256, 0, stream>>>((const float4*)W, WBv, zp);
        dim3 grid(kN / 256, kM / 256);            // (4, 128)
        wsib_gemm_v10<<<grid, 512, 0, stream>>>(
            words, sents, (const uint8_t*)WBv, bias, smap,
            (const uint8_t*)(ws + WS_ZP), out);
    } else {
        dim3 grid(kN / TILE_N, kM / TILE_M);
        wsib_gemm_fb<<<grid, 256, 0, stream>>>(words, sents, W, bias, smap, out);
    }
}